// Round 3
// baseline (312.098 us; speedup 1.0000x reference)
//
#include <hip/hip_runtime.h>
#include <stdint.h>

typedef unsigned long long u64;

#define CIN    256
#define COUT   256
#define HW     56
#define NPIX   (HW * HW)        // 3136
#define PADW   58
#define PPIX   (PADW * PADW)    // 3364
#define NBATCH 32

// ---------------------------------------------------------------------------
// Pack sign(x) bits along Cin into u64 words in a zero-padded 58x58 grid.
// Block = 256 consecutive pixels of one (n, q); a wave reads 64 consecutive
// pixels of one channel per load instr => 256B contiguous (full lines).
// ---------------------------------------------------------------------------
__global__ __launch_bounds__(256) void pack_x_kernel(const float* __restrict__ x,
                                                     u64* __restrict__ xb) {
    int p = blockIdx.x * 256 + threadIdx.x;
    int n = blockIdx.y;
    int q = blockIdx.z;
    if (p >= NPIX) return;
    const float* xp = x + ((size_t)(n * CIN + q * 64)) * NPIX + p;
    u64 word = 0;
#pragma unroll
    for (int j = 0; j < 64; ++j) {
        word |= (u64)(xp[(size_t)j * NPIX] > 0.0f) << j;
    }
    int h = p / HW, w = p % HW;
    xb[((size_t)n * PPIX + (size_t)(h + 1) * PADW + (w + 1)) * 4 + q] = word;
}

// ---------------------------------------------------------------------------
// Fused pack-W + epilogue-constant kernel. One block (1 wave) per cout.
// Lane j holds w[co][q*64+j][k]; __ballot(v>0) across the 64 lanes IS the
// packed u64 word.
//   out = A[co][cls] - B[co]*popc_total ;  A = alpha*(256*vcnt + 2*wcl),
//   B = 2*alpha. cls = border class (h==0 / interior / h==55) x (same for w).
// ---------------------------------------------------------------------------
__global__ __launch_bounds__(64) void packw_ab_kernel(const float* __restrict__ wt,
                                                      const float* __restrict__ alpha,
                                                      u64* __restrict__ wb,
                                                      float* __restrict__ A,
                                                      float* __restrict__ B) {
    int co   = blockIdx.x;
    int lane = threadIdx.x;
    u64 myword = 0;
    int kpop[9];
#pragma unroll
    for (int k = 0; k < 9; ++k) {
        int kp = 0;
#pragma unroll
        for (int q = 0; q < 4; ++q) {
            float v = wt[((size_t)(co * CIN + q * 64 + lane)) * 9 + k];
            u64 mask = __ballot(v > 0.0f);
            kp += __popcll(mask);
            if (lane == k * 4 + q) myword = mask;
        }
        kpop[k] = kp;
    }
    if (lane < 36) wb[(size_t)co * 36 + lane] = myword;
    float al = alpha[co];
    if (lane == 0) B[co] = 2.0f * al;
    if (lane < 9) {
        int ch = lane / 3, cw = lane % 3;
        int wcl = 0, vcnt = 0;
#pragma unroll
        for (int k = 0; k < 9; ++k) {
            int kh = k / 3, kw = k % 3;
            bool inv = (kh == 0 && ch == 0) || (kh == 2 && ch == 2) ||
                       (kw == 0 && cw == 0) || (kw == 2 && cw == 2);
            if (inv) wcl += kpop[k]; else vcnt++;
        }
        A[co * 9 + lane] = al * (float)(256 * vcnt + 2 * wcl);
    }
}

// ---------------------------------------------------------------------------
// XNOR conv. Thread = one output pixel, loops over 64 couts (grid.z chunks).
// r2 lesson: __launch_bounds__ caps VGPRs but doesn't force residency — the
// compiler chose 48 VGPR and rematerialized the 36 xn loads every co-iter
// (~2x VALU). Fix: pin each xn word with an empty asm "+v" — the asm
// "produces" the value, so the load can't be rematerialized; uses read the
// pinned VGPR pair. ~110 VGPR < 128 cap => no spills.
// ---------------------------------------------------------------------------
__global__ __launch_bounds__(256, 4) void conv_kernel(const u64* __restrict__ xb,
                                                      const u64* __restrict__ wb,
                                                      const float* __restrict__ A,
                                                      const float* __restrict__ B,
                                                      float* __restrict__ out) {
    int tid   = threadIdx.x;
    int ptile = blockIdx.x;     // 13 tiles of 256 pixels
    int n     = blockIdx.y;     // 32
    int chunk = blockIdx.z;     // 4 chunks of 64 couts
    int p = ptile * 256 + tid;
    if (p >= NPIX) return;
    int h = p / HW, w = p % HW;

    // padded grid: output (h,w) needs padded rows h..h+2, cols w..w+2.
    // Per row dh: 12 consecutive u64 (dw=0..2, q=0..3) = 96B contiguous.
    u64 xn[9][4];
    const u64* xbase = xb + ((size_t)n * PPIX + (size_t)h * PADW + w) * 4;
#pragma unroll
    for (int dh = 0; dh < 3; ++dh)
#pragma unroll
        for (int dw = 0; dw < 3; ++dw)
#pragma unroll
            for (int q = 0; q < 4; ++q)
                xn[dh * 3 + dw][q] = xbase[((size_t)dh * PADW + dw) * 4 + q];

    // Pin all 36 words in VGPRs (prevents rematerialization of the loads).
#pragma unroll
    for (int k = 0; k < 9; ++k)
#pragma unroll
        for (int q = 0; q < 4; ++q)
            asm volatile("" : "+v"(xn[k][q]));

    int ch  = (h == 0) ? 0 : ((h == HW - 1) ? 2 : 1);
    int cw  = (w == 0) ? 0 : ((w == HW - 1) ? 2 : 1);
    int cls = ch * 3 + cw;

    int co0 = chunk * 64;
    const u64*   wp = wb + (size_t)co0 * 36;
    float*       op = out + ((size_t)(n * COUT + co0)) * NPIX + p;
    const float* Ap = A + co0 * 9 + cls;
    const float* Bp = B + co0;

    for (int c = 0; c < 64; ++c) {
        int acc[4] = {0, 0, 0, 0};
#pragma unroll
        for (int k = 0; k < 9; ++k) {
#pragma unroll
            for (int q = 0; q < 4; ++q) {
                acc[q] += __popcll(xn[k][q] ^ wp[k * 4 + q]);
            }
        }
        int pc = (acc[0] + acc[1]) + (acc[2] + acc[3]);
        op[0] = Ap[c * 9] - Bp[c] * (float)pc;
        op += NPIX;
        wp += 36;
    }
}

// ---------------------------------------------------------------------------
extern "C" void kernel_launch(void* const* d_in, const int* in_sizes, int n_in,
                              void* d_out, int out_size, void* d_ws, size_t ws_size,
                              hipStream_t stream) {
    const float* x     = (const float*)d_in[0];
    const float* wt    = (const float*)d_in[1];
    const float* alpha = (const float*)d_in[2];
    float* out = (float*)d_out;

    char* ws = (char*)d_ws;
    u64* xb = (u64*)ws;                                       // 3,444,736 B
    size_t xb_bytes = (size_t)NBATCH * PPIX * 4 * sizeof(u64);
    u64* wb = (u64*)(ws + xb_bytes);                          // 73,728 B
    size_t wb_bytes = (size_t)COUT * 9 * 4 * sizeof(u64);
    float* A = (float*)(ws + xb_bytes + wb_bytes);            // 9,216 B
    float* B = A + COUT * 9;                                  // 1,024 B

    // zero the padded bit-grid (border ring must be 0 each call; ws is poisoned)
    hipMemsetAsync(xb, 0, xb_bytes, stream);

    pack_x_kernel<<<dim3(13, NBATCH, 4), 256, 0, stream>>>(x, xb);
    packw_ab_kernel<<<dim3(COUT), 64, 0, stream>>>(wt, alpha, wb, A, B);
    conv_kernel<<<dim3(13, NBATCH, 4), 256, 0, stream>>>(xb, wb, A, B, out);
}

// Round 4
// 265.937 us; speedup vs baseline: 1.1736x; 1.1736x over previous
//
#include <hip/hip_runtime.h>
#include <stdint.h>

typedef int i32x4  __attribute__((ext_vector_type(4)));
typedef int i32x16 __attribute__((ext_vector_type(16)));

#define HW     56
#define NPIX   3136            // 56*56
#define PADW   58
#define PPIX   3364            // 58*58
#define NB     32
#define CIN    256
#define COUT   256
#define STRW   32              // bytes per (pixel, g) i8 slice
#define ROWB   (PADW*STRW)     // 1856
#define GSTR   (PPIX*STRW)     // 107648 per (n,g) plane
#define NSTR   (8*GSTR)        // 861184 per n
#define NKID   72              // 8 ci-groups * 9 taps

// ---------------------------------------------------------------------------
// Pack sign(x) to i8 (+1/-1) in layout xsp[n][g][hh][ww][32], zero border
// ring (=> conv padding is exact, no correction terms). Covers ALL padded
// pixels, so no memset dispatch needed. Reads: lanes = consecutive pixels
// (coalesced 4B*64); writes: 32B contiguous per thread (2x dwordx4).
// ---------------------------------------------------------------------------
__global__ __launch_bounds__(256) void pack_x(const float* __restrict__ x,
                                              char* __restrict__ xsp) {
    int pp = blockIdx.x * 256 + threadIdx.x;
    if (pp >= PPIX) return;
    int n = blockIdx.y, g = blockIdx.z;
    int hh = pp / PADW, ww = pp % PADW;
    char* dst = xsp + (size_t)n * NSTR + (size_t)g * GSTR + (size_t)pp * STRW;
    unsigned int wd[8];
    if (hh == 0 || hh == PADW - 1 || ww == 0 || ww == PADW - 1) {
#pragma unroll
        for (int m = 0; m < 8; ++m) wd[m] = 0u;
    } else {
        const float* xp = x + ((size_t)(n * CIN + g * 32)) * NPIX
                            + (size_t)(hh - 1) * HW + (ww - 1);
#pragma unroll
        for (int m = 0; m < 8; ++m) {
            unsigned int v = 0;
#pragma unroll
            for (int jj = 0; jj < 4; ++jj) {
                unsigned int b = (xp[(size_t)(m * 4 + jj) * NPIX] > 0.0f) ? 0x01u : 0xFFu;
                v |= b << (8 * jj);
            }
            wd[m] = v;
        }
    }
    ((i32x4*)dst)[0] = *(i32x4*)&wd[0];
    ((i32x4*)dst)[1] = *(i32x4*)&wd[4];
}

// ---------------------------------------------------------------------------
// Pack sign(W) to wsp[kidx][s][co][16] i8, kidx = g*9 + kh*3 + kw, s = k-half.
// This k-major layout makes the conv's LDS A-tile reads conflict-free
// (lane-consecutive 16B slots) with zero read-side swizzle.
// ---------------------------------------------------------------------------
__global__ __launch_bounds__(256) void pack_w(const float* __restrict__ wt,
                                              char* __restrict__ wsp) {
    int b  = blockIdx.x;         // kidx
    int co = threadIdx.x;
    int g  = b / 9, r = b % 9;   // r = kh*3+kw
    const float* wp = wt + ((size_t)co * CIN + g * 32) * 9 + r;
#pragma unroll
    for (int s = 0; s < 2; ++s) {
        unsigned int wd[4];
#pragma unroll
        for (int m = 0; m < 4; ++m) {
            unsigned int v = 0;
#pragma unroll
            for (int jj = 0; jj < 4; ++jj) {
                unsigned int bb = (wp[(size_t)(s * 16 + m * 4 + jj) * 9] > 0.0f) ? 0x01u : 0xFFu;
                v |= bb << (8 * jj);
            }
            wd[m] = v;
        }
        *(i32x4*)(wsp + ((size_t)(b * 2 + s) * COUT + co) * 16) = *(i32x4*)wd;
    }
}

// ---------------------------------------------------------------------------
__device__ inline void gload16(const void* g, void* l) {
    __builtin_amdgcn_global_load_lds(
        (const __attribute__((address_space(1))) unsigned int*)g,
        (__attribute__((address_space(3))) unsigned int*)l, 16, 0, 0);
}

// ---------------------------------------------------------------------------
// Implicit-GEMM XNOR conv via mfma_i32_32x32x32_i8.
//   A = signs(W): M=co (BM=128), B = im2col signs(x): N=pixels (BN=128),
//   K = 2304 in 72 steps of 32 (g,kh,kw loop). Zero padding => exact.
// 4 waves; wave = 128co x 32pix = 4 MFMA/step, acc 4x16 i32.
// LDS tiles k-major [s=2][row128][16B]: frag read addr = (l>>5)*2048 +
// row*16 -> lane-consecutive slots, conflict-free ds_read_b128.
// Double-buffered, m97-style 2-phase (stage next || compute cur).
// Fragment maps (m74/m93/m101-verified family): A row=l&31, k=(l>>5)*16+e;
// D col=l&31 (pixel), row=(reg&3)+8*(reg>>2)+4*(l>>5) (co).
// ---------------------------------------------------------------------------
__global__ __launch_bounds__(256, 2) void conv_mfma(const char* __restrict__ xsp,
                                                    const char* __restrict__ wsp,
                                                    const float* __restrict__ alpha,
                                                    float* __restrict__ out) {
    __shared__ char lA[2][4096];
    __shared__ char lB[2][4096];
    int tid   = threadIdx.x;
    int ptile = blockIdx.x;     // 784 pixel tiles (784*128 = 100352 exact)
    int mtile = blockIdx.y;     // 2 co tiles
    int t7 = tid >> 7, t127 = tid & 127;

    // A staging source: per-thread constant offset within each kidx chunk
    size_t aoff = (size_t)t7 * 4096 + (size_t)(mtile * 128 + t127) * 16;
    // B staging source: per-thread pixel base (im2col, per-lane address)
    int pix = ptile * 128 + t127;
    int n = pix / NPIX, pq = pix % NPIX;
    int h = pq / HW, w = pq % HW;
    size_t boff = (size_t)n * NSTR + (size_t)h * ROWB + (size_t)w * STRW + (size_t)t7 * 16;

    i32x16 acc[4] = {};

    // prologue: stage k=0 (g=0,kh=0,kw=0)
    gload16(wsp + aoff, &lA[0][tid * 16]);
    gload16(xsp + boff, &lB[0][tid * 16]);
    __syncthreads();   // compiler drains vmcnt(0) before s_barrier

    int l = tid & 63, wv = tid >> 6;
    int s2048  = (l >> 5) * 2048;
    int l31_16 = (l & 31) * 16;

    for (int k = 0; k < NKID; ++k) {
        int buf = k & 1;
        if (k < NKID - 1) {
            int kn = k + 1;
            int g = kn / 9, r = kn % 9, kh = r / 3, kw = r % 3;
            gload16(wsp + (size_t)kn * 8192 + aoff, &lA[buf ^ 1][tid * 16]);
            gload16(xsp + boff + (size_t)g * GSTR + (size_t)kh * ROWB + (size_t)kw * STRW,
                    &lB[buf ^ 1][tid * 16]);
        }
        i32x4 bfrag = *(const i32x4*)&lB[buf][s2048 + wv * 512 + l31_16];
        i32x4 af[4];
#pragma unroll
        for (int mi = 0; mi < 4; ++mi)
            af[mi] = *(const i32x4*)&lA[buf][s2048 + mi * 512 + l31_16];
#pragma unroll
        for (int mi = 0; mi < 4; ++mi)
            acc[mi] = __builtin_amdgcn_mfma_i32_32x32x32_i8(af[mi], bfrag, acc[mi], 0, 0, 0);
        __syncthreads();
    }

    // epilogue: D col = pixel (lane-contiguous stores), row = co
    int hi = l >> 5;
    int pixo = ptile * 128 + wv * 32 + (l & 31);
    int on = pixo / NPIX, opp = pixo % NPIX;
    float* ob = out + (size_t)on * COUT * NPIX + opp;
#pragma unroll
    for (int mi = 0; mi < 4; ++mi) {
#pragma unroll
        for (int r = 0; r < 16; ++r) {
            int co = mtile * 128 + mi * 32 + (r & 3) + 8 * (r >> 2) + 4 * hi;
            ob[(size_t)co * NPIX] = alpha[co] * (float)acc[mi][r];
        }
    }
}

// ---------------------------------------------------------------------------
extern "C" void kernel_launch(void* const* d_in, const int* in_sizes, int n_in,
                              void* d_out, int out_size, void* d_ws, size_t ws_size,
                              hipStream_t stream) {
    const float* x     = (const float*)d_in[0];
    const float* wt    = (const float*)d_in[1];
    const float* alpha = (const float*)d_in[2];
    float* out = (float*)d_out;

    char* ws  = (char*)d_ws;
    char* xsp = ws;                                   // 32*861184 = 27,557,888 B
    char* wsp = ws + (size_t)NB * NSTR;               // 72*8192   =    589,824 B

    pack_x<<<dim3(14, NB, 8), 256, 0, stream>>>(x, xsp);
    pack_w<<<dim3(NKID), 256, 0, stream>>>(wt, wsp);
    conv_mfma<<<dim3(784, 2), 256, 0, stream>>>(xsp, wsp, alpha, out);
}